// Round 6
// baseline (244.098 us; speedup 1.0000x reference)
//
#include <hip/hip_runtime.h>

// ---------- types ----------
typedef unsigned short u16;
typedef __bf16 bf16x8 __attribute__((ext_vector_type(8)));
typedef float f32x4 __attribute__((ext_vector_type(4)));
typedef float f32x16 __attribute__((ext_vector_type(16)));
typedef float float4v __attribute__((ext_vector_type(4)));
typedef unsigned short u16x8 __attribute__((ext_vector_type(8)));
typedef unsigned short u16x4 __attribute__((ext_vector_type(4)));

#define MFMA16(a, b, c) __builtin_amdgcn_mfma_f32_16x16x32_bf16(a, b, c, 0, 0, 0)
#define MFMA32(a, b, c) __builtin_amdgcn_mfma_f32_32x32x16_bf16(a, b, c, 0, 0, 0)

__device__ __forceinline__ u16 f2bf(float f) {
  union { float f; unsigned u; } v; v.f = f;
  unsigned r = v.u + 0x7fffu + ((v.u >> 16) & 1u);
  return (u16)(r >> 16);
}
__device__ __forceinline__ float bf2f(u16 b) {
  union { unsigned u; float f; } v; v.u = ((unsigned)b) << 16;
  return v.f;
}

// async global->LDS, 16B per lane; LDS dest must be wave-uniform base + lane*16
__device__ __forceinline__ void gload16(const void* g, void* l) {
  __builtin_amdgcn_global_load_lds(
      (__attribute__((address_space(1))) void*)g,
      (__attribute__((address_space(3))) void*)l, 16, 0, 0);
}

__device__ __forceinline__ unsigned cvtpk(float lo, float hi) {
  unsigned r;
  asm("v_cvt_pk_bf16_f32 %0, %1, %2" : "=v"(r) : "v"(lo), "v"(hi));
  return r;
}
// swap a.lanes[32:63] <-> b.lanes[0:31]
__device__ __forceinline__ void plswap(unsigned& a, unsigned& b) {
  asm volatile("v_permlane32_swap_b32 %0, %1" : "+v"(a), "+v"(b));
}

// ---------- kernel 1: prep ----------
// Wfused = W3·cw (f32, exact), bias' = W3·cb + b3; also f_w -> bf16.
// W3 = [tw; pw; gw] rows. Blocks 0..767: one Wfused row each. Blocks 768..831: f_w cvt.
__global__ __launch_bounds__(256) void prep_k(
    const float* __restrict__ cw, const float* __restrict__ tw,
    const float* __restrict__ pw, const float* __restrict__ gw,
    const float* __restrict__ cb, const float* __restrict__ tb,
    const float* __restrict__ pb, const float* __restrict__ gb,
    const float* __restrict__ fw,
    u16* __restrict__ Wf, float* __restrict__ biasp, u16* __restrict__ fwb) {
  const int t = threadIdx.x;
  const int bid = blockIdx.x;
  if (bid >= 768) {
    const int idx = (bid - 768) * 256 + t;  // 16384 float4 units
    float4v v = *(const float4v*)(fw + (size_t)idx * 4);
    u16x4 o;
#pragma unroll
    for (int i = 0; i < 4; ++i) o[i] = f2bf(v[i]);
    *(u16x4*)(fwb + (size_t)idx * 4) = o;
    return;
  }
  const int n3 = bid;
  const float* w3 = n3 < 256 ? tw + (size_t)n3 * 256
                  : n3 < 512 ? pw + (size_t)(n3 - 256) * 256
                             : gw + (size_t)(n3 - 512) * 256;
  const float b3 = n3 < 256 ? tb[n3] : n3 < 512 ? pb[n3 - 256] : gb[n3 - 512];
  __shared__ float w3s[256];
  w3s[t] = w3[t];
  __syncthreads();
  float acc = 0.0f;
#pragma unroll 8
  for (int h = 0; h < 256; ++h) acc = fmaf(w3s[h], cw[(size_t)h * 256 + t], acc);
  Wf[(size_t)n3 * 256 + t] = f2bf(acc);
  // bias' = dot(w3, cb) + b3
  float pv = w3s[t] * cb[t];
#pragma unroll
  for (int m = 1; m < 64; m <<= 1) pv += __shfl_xor(pv, m, 64);
  __shared__ float red[4];
  if ((t & 63) == 0) red[t >> 6] = pv;
  __syncthreads();
  if (t == 0) biasp[n3] = red[0] + red[1] + red[2] + red[3] + b3;
}

// ---------- kernel 2: tpg GEMM with fused f32->bf16 A conversion ----------
// tpg[m][n3] = x[m][:]·Wf[n3][:] + bias'[n3]; A staged reg-cvt into XOR-swizzled As.
__global__ __launch_bounds__(256) void gemm_tpg(
    const float* __restrict__ X, const u16* __restrict__ W,
    const float* __restrict__ bias, u16* __restrict__ Cout) {
  __shared__ u16 As[8192];
  __shared__ u16 Bs[8192];
  const int t = threadIdx.x;
  const int lane = t & 63, w = t >> 6;
  const int brow = blockIdx.x * 128, bcol = blockIdx.y * 128;
  const int wr = (w >> 1) * 64, wc = (w & 1) * 64;
  f32x4 acc[4][4];
#pragma unroll
  for (int i = 0; i < 4; ++i)
#pragma unroll
    for (int j = 0; j < 4; ++j)
#pragma unroll
      for (int r = 0; r < 4; ++r) acc[i][j][r] = 0.0f;

  const int sr = t >> 3, sc8 = (t & 7) * 8;
  const u16* gW = W + (size_t)(bcol + sr) * 256 + sc8;
  const int ar = t & 127, ach = t >> 7;  // A staging: row, col-half
  const float* gX = X + (size_t)(brow + ar) * 256 + ach * 32;

  for (int kt = 0; kt < 256; kt += 64) {
    // B: async to LDS (linear)
#pragma unroll
    for (int c = 0; c < 4; ++c)
      gload16(gW + (size_t)c * 32 * 256 + kt, &Bs[c * 2048 + t * 8]);
    // A: f32 load -> cvt -> swizzled ds_write
    u16x8 pk[4];
#pragma unroll
    for (int j = 0; j < 4; ++j) {
      float4v v0 = *(const float4v*)(gX + kt + j * 8);
      float4v v1 = *(const float4v*)(gX + kt + j * 8 + 4);
#pragma unroll
      for (int e = 0; e < 4; ++e) { pk[j][e] = f2bf(v0[e]); pk[j][4 + e] = f2bf(v1[e]); }
    }
#pragma unroll
    for (int j = 0; j < 4; ++j) {
      int unit = (ach * 4 + j) ^ (ar & 7);
      *(u16x8*)(&As[ar * 64 + unit * 8]) = pk[j];
    }
    __syncthreads();
#pragma unroll
    for (int kk = 0; kk < 2; ++kk) {
      const int ko = kk * 32 + (lane >> 4) * 8;
      bf16x8 af[4], bfr[4];
#pragma unroll
      for (int i = 0; i < 4; ++i) {
        int R = wr + i * 16 + (lane & 15);
        int unit = (kk * 4 + (lane >> 4)) ^ (R & 7);
        af[i] = *(const bf16x8*)(&As[R * 64 + unit * 8]);
      }
#pragma unroll
      for (int j = 0; j < 4; ++j)
        bfr[j] = *(const bf16x8*)(&Bs[(wc + j * 16 + (lane & 15)) * 64 + ko]);
#pragma unroll
      for (int i = 0; i < 4; ++i)
#pragma unroll
        for (int j = 0; j < 4; ++j)
          acc[i][j] = MFMA16(af[i], bfr[j], acc[i][j]);
    }
    __syncthreads();
  }

  const int r0 = (lane >> 4) * 4, c0 = lane & 15;
#pragma unroll
  for (int i = 0; i < 4; ++i)
#pragma unroll
    for (int j = 0; j < 4; ++j) {
      const int col = bcol + wc + j * 16 + c0;
      const float bv = bias[col];
#pragma unroll
      for (int r = 0; r < 4; ++r) {
        const size_t o = (size_t)(brow + wr + i * 16 + r0 + r) * 768 + col;
        Cout[o] = f2bf(acc[i][j][r] + bv);
      }
    }
}

// ---------- kernel 3: transpose g -> gT[b][k][m] ----------
__global__ __launch_bounds__(256) void transpose_g_k(
    const u16* __restrict__ tpg, u16* __restrict__ gT) {
  __shared__ u16 T[64][65];
  const int t = threadIdx.x;
  const int bm = (blockIdx.x & 63) * 64;
  const int bk = ((blockIdx.x >> 6) & 3) * 64;
  const int b = blockIdx.x >> 8;
  const int r = t >> 3, c8 = (t & 7) * 8;
#pragma unroll
  for (int ch = 0; ch < 2; ++ch) {
    u16x8 v = *(const u16x8*)(tpg + (size_t)(b * 4096 + bm + r + ch * 32) * 768 + 512 + bk + c8);
#pragma unroll
    for (int j = 0; j < 8; ++j) T[r + ch * 32][c8 + j] = v[j];
  }
  __syncthreads();
#pragma unroll
  for (int ch = 0; ch < 2; ++ch) {
    u16x8 o;
#pragma unroll
    for (int j = 0; j < 8; ++j) o[j] = T[c8 + j][r + ch * 32];
    *(u16x8*)(gT + (size_t)(b * 256 + bk + r + ch * 32) * 4096 + bm + c8) = o;
  }
}

// ---------- kernel 4: flash attention v4 (QK^T split into 2 MFMA chains) ----------
__global__ __launch_bounds__(256, 2) void flash2(
    const u16* __restrict__ tpg, const u16* __restrict__ gT,
    u16* __restrict__ Zp, u16* __restrict__ Lpb) {
  __shared__ u16 Kl[2][32 * 256];  // rows=kv(32), swz c16^row
  __shared__ u16 Vl[2][256 * 32];  // rows=d(256), swz c16^((row>>1)&3)

  const int t = threadIdx.x;
  const int lane = t & 63, w = t >> 6;
  const int l31 = lane & 31, hi = lane >> 5;
  const int bid = blockIdx.x;
  const int b = bid >> 7;
  const int quarter = (bid >> 5) & 3;
  const int qt = bid & 31;
  const int q0 = qt * 128 + w * 32;
  const int kv0 = quarter * 1024;

  bf16x8 q[16];
  {
    const u16* qp = tpg + (size_t)(b * 4096 + q0 + l31) * 768 + hi * 8;
#pragma unroll
    for (int ks = 0; ks < 16; ++ks) q[ks] = *(const bf16x8*)(qp + ks * 16);
  }

  f32x16 zacc[8];
#pragma unroll
  for (int i = 0; i < 8; ++i)
#pragma unroll
    for (int j = 0; j < 16; ++j) zacc[i][j] = 0.0f;
  float ell = 0.0f;

  const int ksr = t >> 5, ksc = t & 31;

  auto stage = [&](int tile, int bi) {
    const size_t krow0 = (size_t)(b * 4096 + kv0 + tile * 32);
#pragma unroll
    for (int ch = 0; ch < 4; ++ch) {
      int r = ch * 8 + ksr;
      gload16(tpg + (krow0 + r) * 768 + 256 + ((ksc ^ r) * 8), &Kl[bi][ch * 2048 + t * 8]);
    }
#pragma unroll
    for (int ch = 0; ch < 4; ++ch) {
      int u = ch * 256 + t;
      int r = u >> 2, c16 = u & 3;
      gload16(gT + (size_t)(b * 256 + r) * 4096 + kv0 + tile * 32 + ((c16 ^ ((r >> 1) & 3)) * 8),
              &Vl[bi][u * 8]);
    }
  };

  stage(0, 0);
  __syncthreads();

  for (int tile = 0; tile < 32; ++tile) {
    const int cur = tile & 1;
    if (tile + 1 < 32) stage(tile + 1, cur ^ 1);

    // S^T = K * Q^T : two independent accumulation chains of 8
    f32x16 s0, s1;
#pragma unroll
    for (int j = 0; j < 16; ++j) { s0[j] = 0.0f; s1[j] = 0.0f; }
    const u16* kb = &Kl[cur][0];
    __builtin_amdgcn_s_setprio(1);
#pragma unroll
    for (int ks = 0; ks < 8; ++ks) {
      bf16x8 kfa = *(const bf16x8*)(kb + l31 * 256 + (((2 * ks + hi) ^ l31) * 8));
      bf16x8 kfb = *(const bf16x8*)(kb + l31 * 256 + (((2 * (ks + 8) + hi) ^ l31) * 8));
      s0 = MFMA32(kfa, q[ks], s0);
      s1 = MFMA32(kfb, q[ks + 8], s1);
    }
    __builtin_amdgcn_s_setprio(0);
#pragma unroll
    for (int j = 0; j < 16; ++j) s0[j] += s1[j];

    // in-register softmax numerators -> PV A-frags
    bf16x8 pa[2];
#pragma unroll
    for (int half = 0; half < 2; ++half) {
      float p[8];
#pragma unroll
      for (int g = 0; g < 8; ++g) {
        p[g] = __builtin_amdgcn_exp2f(s0[half * 8 + g] * 0.09016844f);
        ell += p[g];
      }
      unsigned x0 = cvtpk(p[0], p[1]), y0 = cvtpk(p[4], p[5]);
      unsigned x1 = cvtpk(p[2], p[3]), y1 = cvtpk(p[6], p[7]);
      plswap(x0, y0);
      plswap(x1, y1);
      union { unsigned u[4]; bf16x8 v; } cc;
      cc.u[0] = x0; cc.u[1] = x1; cc.u[2] = y0; cc.u[3] = y1;
      pa[half] = cc.v;
    }

    // Z += P * V
    const u16* vb = &Vl[cur][0];
    __builtin_amdgcn_s_setprio(1);
#pragma unroll
    for (int ks2 = 0; ks2 < 2; ++ks2) {
#pragma unroll
      for (int nt = 0; nt < 8; ++nt) {
        int row = nt * 32 + l31;
        bf16x8 vv = *(const bf16x8*)(vb + row * 32 + (((2 * ks2 + hi) ^ ((row >> 1) & 3)) * 8));
        zacc[nt] = MFMA32(pa[ks2], vv, zacc[nt]);
      }
    }
    __builtin_amdgcn_s_setprio(0);
    __syncthreads();
  }

  ell += __shfl_xor(ell, 32, 64);

#pragma unroll
  for (int g = 0; g < 16; ++g) {
    int r = (g & 3) + 8 * (g >> 2) + 4 * hi;
    size_t rowoff = ((size_t)(quarter * 16384 + b * 4096 + q0 + r)) * 256 + l31;
#pragma unroll
    for (int nt = 0; nt < 8; ++nt) Zp[rowoff + nt * 32] = f2bf(zacc[nt][g]);
  }
  if (lane < 32) Lpb[quarter * 16384 + b * 4096 + q0 + l31] = f2bf(ell);
}

// ---------- kernel 5: final GEMM with fused merge/normalize + residual ----------
__global__ __launch_bounds__(256) void gemm_out(
    const u16* __restrict__ Zp, const u16* __restrict__ Lpb,
    const u16* __restrict__ W, const float* __restrict__ bias,
    float* __restrict__ Cout, const float* __restrict__ res) {
  __shared__ u16 As[8192];
  __shared__ u16 Bs[8192];
  const int t = threadIdx.x;
  const int lane = t & 63, w = t >> 6;
  const int brow = blockIdx.x * 128, bcol = blockIdx.y * 128;
  const int wr = (w >> 1) * 64, wc = (w & 1) * 64;
  f32x4 acc[4][4];
#pragma unroll
  for (int i = 0; i < 4; ++i)
#pragma unroll
    for (int j = 0; j < 4; ++j)
#pragma unroll
      for (int r = 0; r < 4; ++r) acc[i][j][r] = 0.0f;

  const int sr = t >> 3, sc8 = (t & 7) * 8;
  const u16* gW = W + (size_t)(bcol + sr) * 256 + sc8;
  const int ar = t >> 1, ach = t & 1;  // A staging: row 0..127, col-half
  const int am = brow + ar;
  const float linv = 1.0f /
      ((bf2f(Lpb[am]) + bf2f(Lpb[16384 + am]) + bf2f(Lpb[32768 + am]) + bf2f(Lpb[49152 + am])) *
       64.0f);

  for (int kt = 0; kt < 256; kt += 64) {
#pragma unroll
    for (int c = 0; c < 4; ++c)
      gload16(gW + (size_t)c * 32 * 256 + kt, &Bs[c * 2048 + t * 8]);
    // A: merge 4 partials -> normalize -> bf16 -> swizzled ds_write
    const int col0 = kt + ach * 32;
    float sacc[32];
#pragma unroll
    for (int e = 0; e < 32; ++e) sacc[e] = 0.0f;
#pragma unroll
    for (int qd = 0; qd < 4; ++qd) {
      const u16* zp = Zp + ((size_t)(qd * 16384) + am) * 256 + col0;
#pragma unroll
      for (int j = 0; j < 4; ++j) {
        u16x8 v = *(const u16x8*)(zp + j * 8);
#pragma unroll
        for (int e = 0; e < 8; ++e) sacc[j * 8 + e] += bf2f(v[e]);
      }
    }
#pragma unroll
    for (int j = 0; j < 4; ++j) {
      u16x8 pk;
#pragma unroll
      for (int e = 0; e < 8; ++e) pk[e] = f2bf(sacc[j * 8 + e] * linv);
      int unit = (ach * 4 + j) ^ (ar & 7);
      *(u16x8*)(&As[ar * 64 + unit * 8]) = pk;
    }
    __syncthreads();
#pragma unroll
    for (int kk = 0; kk < 2; ++kk) {
      const int ko = kk * 32 + (lane >> 4) * 8;
      bf16x8 af[4], bfr[4];
#pragma unroll
      for (int i = 0; i < 4; ++i) {
        int R = wr + i * 16 + (lane & 15);
        int unit = (kk * 4 + (lane >> 4)) ^ (R & 7);
        af[i] = *(const bf16x8*)(&As[R * 64 + unit * 8]);
      }
#pragma unroll
      for (int j = 0; j < 4; ++j)
        bfr[j] = *(const bf16x8*)(&Bs[(wc + j * 16 + (lane & 15)) * 64 + ko]);
#pragma unroll
      for (int i = 0; i < 4; ++i)
#pragma unroll
        for (int j = 0; j < 4; ++j)
          acc[i][j] = MFMA16(af[i], bfr[j], acc[i][j]);
    }
    __syncthreads();
  }

  const int r0 = (lane >> 4) * 4, c0 = lane & 15;
#pragma unroll
  for (int i = 0; i < 4; ++i)
#pragma unroll
    for (int j = 0; j < 4; ++j) {
      const int col = bcol + wc + j * 16 + c0;
      const float bv = bias[col];
#pragma unroll
      for (int r = 0; r < 4; ++r) {
        const size_t o = (size_t)(brow + wr + i * 16 + r0 + r) * 256 + col;
        Cout[o] = acc[i][j][r] + bv + res[o];
      }
    }
}

// ---------- launch ----------
extern "C" void kernel_launch(void* const* d_in, const int* in_sizes, int n_in,
                              void* d_out, int out_size, void* d_ws, size_t ws_size,
                              hipStream_t stream) {
  const float* x  = (const float*)d_in[0];
  const float* cw = (const float*)d_in[1];
  const float* cb = (const float*)d_in[2];
  const float* tw = (const float*)d_in[3];
  const float* tb = (const float*)d_in[4];
  const float* pw = (const float*)d_in[5];
  const float* pb = (const float*)d_in[6];
  const float* gw = (const float*)d_in[7];
  const float* gb = (const float*)d_in[8];
  const float* fw = (const float*)d_in[9];
  const float* fb = (const float*)d_in[10];

  char* ws = (char*)d_ws;
  // layout (peak = 67,767,296 B)
  u16*   tpg   = (u16*)(ws);                  // [16384][768]               25165824 B
  u16*   gT    = (u16*)(ws + 25165824);       // [4][256][4096]              8388608 B
  u16*   Zp    = (u16*)(ws + 33554432);       // [4][16384][256] bf16       33554432 B
  u16*   Lpb   = (u16*)(ws + 67108864);       // [4][16384] bf16              131072 B
  u16*   Wf    = (u16*)(ws + 67239936);       // [768][256] bf16              393216 B
  u16*   fwb   = (u16*)(ws + 67633152);       // [256][256] bf16              131072 B
  float* biasp = (float*)(ws + 67764224);     // [768] f32                      3072 B

  // Wfused = W3·cw, bias' = W3·cb + b3 (f32 exact); f_w -> bf16
  prep_k<<<832, 256, 0, stream>>>(cw, tw, pw, gw, cb, tb, pb, gb, fw, Wf, biasp, fwb);
  // theta|phi|g = x @ Wfused^T + bias'  (one GEMM replaces h-GEMM + tpg-GEMM)
  gemm_tpg<<<dim3(128, 6), 256, 0, stream>>>(x, Wf, biasp, tpg);
  transpose_g_k<<<1024, 256, 0, stream>>>(tpg, gT);
  flash2<<<512, 256, 0, stream>>>(tpg, gT, Zp, Lpb);
  // out = merge(Zp)/L @ f_w^T + f_b + x
  gemm_out<<<dim3(128, 2), 256, 0, stream>>>(Zp, Lpb, fwb, fb, (float*)d_out, x);
}

// Round 7
// 218.655 us; speedup vs baseline: 1.1164x; 1.1164x over previous
//
#include <hip/hip_runtime.h>

// ---------- types ----------
typedef unsigned short u16;
typedef __bf16 bf16x8 __attribute__((ext_vector_type(8)));
typedef float f32x4 __attribute__((ext_vector_type(4)));
typedef float f32x16 __attribute__((ext_vector_type(16)));
typedef float float4v __attribute__((ext_vector_type(4)));
typedef unsigned short u16x8 __attribute__((ext_vector_type(8)));
typedef unsigned short u16x4 __attribute__((ext_vector_type(4)));

#define MFMA16(a, b, c) __builtin_amdgcn_mfma_f32_16x16x32_bf16(a, b, c, 0, 0, 0)
#define MFMA32(a, b, c) __builtin_amdgcn_mfma_f32_32x32x16_bf16(a, b, c, 0, 0, 0)

__device__ __forceinline__ u16 f2bf(float f) {
  union { float f; unsigned u; } v; v.f = f;
  unsigned r = v.u + 0x7fffu + ((v.u >> 16) & 1u);
  return (u16)(r >> 16);
}
__device__ __forceinline__ float bf2f(u16 b) {
  union { unsigned u; float f; } v; v.u = ((unsigned)b) << 16;
  return v.f;
}

// async global->LDS, 16B per lane; LDS dest must be wave-uniform base + lane*16
__device__ __forceinline__ void gload16(const void* g, void* l) {
  __builtin_amdgcn_global_load_lds(
      (__attribute__((address_space(1))) void*)g,
      (__attribute__((address_space(3))) void*)l, 16, 0, 0);
}

__device__ __forceinline__ unsigned cvtpk(float lo, float hi) {
  unsigned r;
  asm("v_cvt_pk_bf16_f32 %0, %1, %2" : "=v"(r) : "v"(lo), "v"(hi));
  return r;
}
// swap a.lanes[32:63] <-> b.lanes[0:31]
__device__ __forceinline__ void plswap(unsigned& a, unsigned& b) {
  asm volatile("v_permlane32_swap_b32 %0, %1" : "+v"(a), "+v"(b));
}

// ---------- kernel 1: prep1 ----------
// bid<256: Wbig[bid]   = row of theta_w·cw (bf16), biasp[bid]   = theta_w·cb + theta_b
// bid<512: Wbig[bid]   = row of phi_w·cw  (bf16), biasp[bid]   = phi_w·cb + phi_b
// else   : Gtmp[bid-512] = row of g_w·cw  (f32),  gvec[bid-512] = g_w·cb + g_b
__global__ __launch_bounds__(256) void prep1(
    const float* __restrict__ cw, const float* __restrict__ tw,
    const float* __restrict__ pw, const float* __restrict__ gw,
    const float* __restrict__ cb, const float* __restrict__ tb,
    const float* __restrict__ pb, const float* __restrict__ gb,
    u16* __restrict__ Wbig, float* __restrict__ biasp,
    float* __restrict__ Gtmp, float* __restrict__ gvec) {
  const int t = threadIdx.x;
  const int bid = blockIdx.x;  // 0..767
  const int n3 = bid & 255;
  const float* wsrc = bid < 256 ? tw : bid < 512 ? pw : gw;
  __shared__ float w3s[256];
  w3s[t] = wsrc[(size_t)n3 * 256 + t];
  __syncthreads();
  float acc = 0.0f;
#pragma unroll 8
  for (int h = 0; h < 256; ++h) acc = fmaf(w3s[h], cw[(size_t)h * 256 + t], acc);
  float pv = w3s[t] * cb[t];
#pragma unroll
  for (int m = 1; m < 64; m <<= 1) pv += __shfl_xor(pv, m, 64);
  __shared__ float red[4];
  if ((t & 63) == 0) red[t >> 6] = pv;
  __syncthreads();
  const float dotcb = red[0] + red[1] + red[2] + red[3];
  if (bid < 512) {
    Wbig[(size_t)bid * 256 + t] = f2bf(acc);
    if (t == 0) biasp[bid] = dotcb + (bid < 256 ? tb[n3] : pb[n3]);
  } else {
    Gtmp[(size_t)n3 * 256 + t] = acc;
    if (t == 0) gvec[n3] = dotcb + gb[n3];
  }
}

// ---------- kernel 2: prep2 ----------
// Wbig[512+o] = row of fw·Gtmp (bf16) ; biasp[512+o] = fw·gvec
__global__ __launch_bounds__(256) void prep2(
    const float* __restrict__ fw, const float* __restrict__ Gtmp,
    const float* __restrict__ gvec, u16* __restrict__ Wbig,
    float* __restrict__ biasp) {
  const int t = threadIdx.x;
  const int o = blockIdx.x;  // 0..255
  __shared__ float fs[256];
  fs[t] = fw[(size_t)o * 256 + t];
  __syncthreads();
  float acc = 0.0f;
#pragma unroll 8
  for (int h = 0; h < 256; ++h) acc = fmaf(fs[h], Gtmp[(size_t)h * 256 + t], acc);
  Wbig[(size_t)(512 + o) * 256 + t] = f2bf(acc);
  float pv = fs[t] * gvec[t];
#pragma unroll
  for (int m = 1; m < 64; m <<= 1) pv += __shfl_xor(pv, m, 64);
  __shared__ float red[4];
  if ((t & 63) == 0) red[t >> 6] = pv;
  __syncthreads();
  if (t == 0) biasp[512 + o] = red[0] + red[1] + red[2] + red[3];
}

// ---------- kernel 3: tpg GEMM, fused f32->bf16 A conversion ----------
// y<4:  tpg[m][col] = x[m]·Wbig[col] + biasp[col]   (theta|phi, stride 512)
// y>=4: gT[b][col-512][m&4095] = same, written TRANSPOSED (V' = g·fw^T folded)
__global__ __launch_bounds__(256) void gemm_tpg(
    const float* __restrict__ X, const u16* __restrict__ W,
    const float* __restrict__ bias, u16* __restrict__ tpg,
    u16* __restrict__ gT) {
  __shared__ u16 As[8192];
  __shared__ u16 Bs[8192];
  const int t = threadIdx.x;
  const int lane = t & 63, w = t >> 6;
  const int brow = blockIdx.x * 128, bcol = blockIdx.y * 128;
  const int wr = (w >> 1) * 64, wc = (w & 1) * 64;
  f32x4 acc[4][4];
#pragma unroll
  for (int i = 0; i < 4; ++i)
#pragma unroll
    for (int j = 0; j < 4; ++j)
#pragma unroll
      for (int r = 0; r < 4; ++r) acc[i][j][r] = 0.0f;

  const int sr = t >> 3, sc8 = (t & 7) * 8;
  const u16* gW = W + (size_t)(bcol + sr) * 256 + sc8;
  const int ar = t & 127, ach = t >> 7;  // A staging: row, col-half
  const float* gX = X + (size_t)(brow + ar) * 256 + ach * 32;

  for (int kt = 0; kt < 256; kt += 64) {
#pragma unroll
    for (int c = 0; c < 4; ++c)
      gload16(gW + (size_t)c * 32 * 256 + kt, &Bs[c * 2048 + t * 8]);
    u16x8 pk[4];
#pragma unroll
    for (int j = 0; j < 4; ++j) {
      float4v v0 = *(const float4v*)(gX + kt + j * 8);
      float4v v1 = *(const float4v*)(gX + kt + j * 8 + 4);
#pragma unroll
      for (int e = 0; e < 4; ++e) { pk[j][e] = f2bf(v0[e]); pk[j][4 + e] = f2bf(v1[e]); }
    }
#pragma unroll
    for (int j = 0; j < 4; ++j) {
      int unit = (ach * 4 + j) ^ (ar & 7);
      *(u16x8*)(&As[ar * 64 + unit * 8]) = pk[j];
    }
    __syncthreads();
#pragma unroll
    for (int kk = 0; kk < 2; ++kk) {
      const int ko = kk * 32 + (lane >> 4) * 8;
      bf16x8 af[4], bfr[4];
#pragma unroll
      for (int i = 0; i < 4; ++i) {
        int R = wr + i * 16 + (lane & 15);
        int unit = (kk * 4 + (lane >> 4)) ^ (R & 7);
        af[i] = *(const bf16x8*)(&As[R * 64 + unit * 8]);
      }
#pragma unroll
      for (int j = 0; j < 4; ++j)
        bfr[j] = *(const bf16x8*)(&Bs[(wc + j * 16 + (lane & 15)) * 64 + ko]);
#pragma unroll
      for (int i = 0; i < 4; ++i)
#pragma unroll
        for (int j = 0; j < 4; ++j)
          acc[i][j] = MFMA16(af[i], bfr[j], acc[i][j]);
    }
    __syncthreads();
  }

  const int r0 = (lane >> 4) * 4, c0 = lane & 15;
  if (blockIdx.y < 4) {
#pragma unroll
    for (int i = 0; i < 4; ++i)
#pragma unroll
      for (int j = 0; j < 4; ++j) {
        const int col = bcol + wc + j * 16 + c0;
        const float bv = bias[col];
#pragma unroll
        for (int r = 0; r < 4; ++r) {
          const size_t o = (size_t)(brow + wr + i * 16 + r0 + r) * 512 + col;
          tpg[o] = f2bf(acc[i][j][r] + bv);
        }
      }
  } else {
#pragma unroll
    for (int i = 0; i < 4; ++i) {
      const int m0 = brow + wr + i * 16 + r0;  // multiple of 4
      const int b = m0 >> 12, n0 = m0 & 4095;
#pragma unroll
      for (int j = 0; j < 4; ++j) {
        const int col = bcol + wc + j * 16 + c0;      // 512..767
        const float bv = bias[col];
        u16x4 ov;
#pragma unroll
        for (int r = 0; r < 4; ++r) ov[r] = f2bf(acc[i][j][r] + bv);
        *(u16x4*)(gT + ((size_t)((b << 8) + (col - 512))) * 4096 + n0) = ov;
      }
    }
  }
}

// ---------- kernel 4: flash attention (round-5 structure, tpg stride 512) ----------
// Swapped QK^T; in-register softmax (cvt_pk + permlane32_swap); V' in gT.
// grid 512 = b(4) x quarter(4) x qtile(32); 4 waves x 32 q-rows.
__global__ __launch_bounds__(256, 2) void flash2(
    const u16* __restrict__ tpg, const u16* __restrict__ gT,
    u16* __restrict__ Zp, u16* __restrict__ Lpb) {
  __shared__ u16 Kl[2][32 * 256];  // rows=kv(32), swz c16^row
  __shared__ u16 Vl[2][256 * 32];  // rows=d(256), swz c16^((row>>1)&3)

  const int t = threadIdx.x;
  const int lane = t & 63, w = t >> 6;
  const int l31 = lane & 31, hi = lane >> 5;
  const int bid = blockIdx.x;
  const int b = bid >> 7;
  const int quarter = (bid >> 5) & 3;
  const int qt = bid & 31;
  const int q0 = qt * 128 + w * 32;
  const int kv0 = quarter * 1024;

  bf16x8 q[16];
  {
    const u16* qp = tpg + (size_t)(b * 4096 + q0 + l31) * 512 + hi * 8;
#pragma unroll
    for (int ks = 0; ks < 16; ++ks) q[ks] = *(const bf16x8*)(qp + ks * 16);
  }

  f32x16 zacc[8];
#pragma unroll
  for (int i = 0; i < 8; ++i)
#pragma unroll
    for (int j = 0; j < 16; ++j) zacc[i][j] = 0.0f;
  float ell = 0.0f;

  const int ksr = t >> 5, ksc = t & 31;

  auto stage = [&](int tile, int bi) {
    const size_t krow0 = (size_t)(b * 4096 + kv0 + tile * 32);
#pragma unroll
    for (int ch = 0; ch < 4; ++ch) {
      int r = ch * 8 + ksr;
      gload16(tpg + (krow0 + r) * 512 + 256 + ((ksc ^ r) * 8), &Kl[bi][ch * 2048 + t * 8]);
    }
#pragma unroll
    for (int ch = 0; ch < 4; ++ch) {
      int u = ch * 256 + t;
      int r = u >> 2, c16 = u & 3;
      gload16(gT + (size_t)(b * 256 + r) * 4096 + kv0 + tile * 32 + ((c16 ^ ((r >> 1) & 3)) * 8),
              &Vl[bi][u * 8]);
    }
  };

  stage(0, 0);
  __syncthreads();

  for (int tile = 0; tile < 32; ++tile) {
    const int cur = tile & 1;
    if (tile + 1 < 32) stage(tile + 1, cur ^ 1);

    // S^T = K * Q^T
    f32x16 s;
#pragma unroll
    for (int j = 0; j < 16; ++j) s[j] = 0.0f;
    const u16* kb = &Kl[cur][0];
    __builtin_amdgcn_s_setprio(1);
#pragma unroll
    for (int ks = 0; ks < 16; ++ks) {
      bf16x8 kf = *(const bf16x8*)(kb + l31 * 256 + (((2 * ks + hi) ^ l31) * 8));
      s = MFMA32(kf, q[ks], s);
    }
    __builtin_amdgcn_s_setprio(0);

    // in-register softmax numerators -> PV A-frags
    bf16x8 pa[2];
#pragma unroll
    for (int half = 0; half < 2; ++half) {
      float p[8];
#pragma unroll
      for (int g = 0; g < 8; ++g) {
        p[g] = __builtin_amdgcn_exp2f(s[half * 8 + g] * 0.09016844f);
        ell += p[g];
      }
      unsigned x0 = cvtpk(p[0], p[1]), y0 = cvtpk(p[4], p[5]);
      unsigned x1 = cvtpk(p[2], p[3]), y1 = cvtpk(p[6], p[7]);
      plswap(x0, y0);
      plswap(x1, y1);
      union { unsigned u[4]; bf16x8 v; } cc;
      cc.u[0] = x0; cc.u[1] = x1; cc.u[2] = y0; cc.u[3] = y1;
      pa[half] = cc.v;
    }

    // Z += P * V'
    const u16* vb = &Vl[cur][0];
    __builtin_amdgcn_s_setprio(1);
#pragma unroll
    for (int ks2 = 0; ks2 < 2; ++ks2) {
#pragma unroll
      for (int nt = 0; nt < 8; ++nt) {
        int row = nt * 32 + l31;
        bf16x8 vv = *(const bf16x8*)(vb + row * 32 + (((2 * ks2 + hi) ^ ((row >> 1) & 3)) * 8));
        zacc[nt] = MFMA32(pa[ks2], vv, zacc[nt]);
      }
    }
    __builtin_amdgcn_s_setprio(0);
    __syncthreads();
  }

  ell += __shfl_xor(ell, 32, 64);

#pragma unroll
  for (int g = 0; g < 16; ++g) {
    int r = (g & 3) + 8 * (g >> 2) + 4 * hi;
    size_t rowoff = ((size_t)(quarter * 16384 + b * 4096 + q0 + r)) * 256 + l31;
#pragma unroll
    for (int nt = 0; nt < 8; ++nt) Zp[rowoff + nt * 32] = f2bf(zacc[nt][g]);
  }
  if (lane < 32) Lpb[quarter * 16384 + b * 4096 + q0 + l31] = f2bf(ell);
}

// ---------- kernel 5: elementwise merge: out = sum(Zp)/(64*sum(L)) + fb + x ----------
__global__ __launch_bounds__(256) void merge_out(
    const u16* __restrict__ Zp, const u16* __restrict__ Lpb,
    const float* __restrict__ fb, const float* __restrict__ x,
    float* __restrict__ out) {
  const int idx = blockIdx.x * 256 + threadIdx.x;  // 524288 threads, 8 cols each
  const int m = idx >> 5;
  const int c = (idx & 31) * 8;
  const float l = bf2f(Lpb[m]) + bf2f(Lpb[16384 + m]) + bf2f(Lpb[32768 + m]) +
                  bf2f(Lpb[49152 + m]);
  const float inv = 1.0f / (l * 64.0f);
  float acc[8];
#pragma unroll
  for (int j = 0; j < 8; ++j) acc[j] = 0.0f;
#pragma unroll
  for (int qd = 0; qd < 4; ++qd) {
    u16x8 v = *(const u16x8*)(Zp + ((size_t)(qd * 16384) + m) * 256 + c);
#pragma unroll
    for (int j = 0; j < 8; ++j) acc[j] += bf2f(v[j]);
  }
  const float4v fb0 = *(const float4v*)(fb + c);
  const float4v fb1 = *(const float4v*)(fb + c + 4);
  const float4v x0 = *(const float4v*)(x + (size_t)m * 256 + c);
  const float4v x1 = *(const float4v*)(x + (size_t)m * 256 + c + 4);
  float4v o0, o1;
#pragma unroll
  for (int j = 0; j < 4; ++j) {
    o0[j] = acc[j] * inv + fb0[j] + x0[j];
    o1[j] = acc[4 + j] * inv + fb1[j] + x1[j];
  }
  *(float4v*)(out + (size_t)m * 256 + c) = o0;
  *(float4v*)(out + (size_t)m * 256 + c + 4) = o1;
}

// ---------- launch ----------
extern "C" void kernel_launch(void* const* d_in, const int* in_sizes, int n_in,
                              void* d_out, int out_size, void* d_ws, size_t ws_size,
                              hipStream_t stream) {
  const float* x  = (const float*)d_in[0];
  const float* cw = (const float*)d_in[1];
  const float* cb = (const float*)d_in[2];
  const float* tw = (const float*)d_in[3];
  const float* tb = (const float*)d_in[4];
  const float* pw = (const float*)d_in[5];
  const float* pb = (const float*)d_in[6];
  const float* gw = (const float*)d_in[7];
  const float* gb = (const float*)d_in[8];
  const float* fw = (const float*)d_in[9];
  const float* fb = (const float*)d_in[10];

  char* ws = (char*)d_ws;
  // layout (peak ~59.5 MB)
  u16*   tpg   = (u16*)(ws);                  // [16384][512] theta|phi     16777216 B
  u16*   gT    = (u16*)(ws + 16777216);       // [4][256][4096] V'           8388608 B
  u16*   Zp    = (u16*)(ws + 25165824);       // [4][16384][256] bf16       33554432 B
  u16*   Lpb   = (u16*)(ws + 58720256);       // [4][16384] bf16              131072 B
  u16*   Wbig  = (u16*)(ws + 58851328);       // [768][256] bf16              393216 B
  float* biasp = (float*)(ws + 59244544);     // [768] f32                      3072 B
  float* Gtmp  = (float*)(ws + 59247616);     // [256][256] f32               262144 B
  float* gvec  = (float*)(ws + 59509760);     // [256] f32                      1024 B

  prep1<<<768, 256, 0, stream>>>(cw, tw, pw, gw, cb, tb, pb, gb,
                                 Wbig, biasp, Gtmp, gvec);
  prep2<<<256, 256, 0, stream>>>(fw, Gtmp, gvec, Wbig, biasp);
  // theta|phi -> tpg (stride 512); V' -> gT (transposed write)
  gemm_tpg<<<dim3(128, 6), 256, 0, stream>>>(x, Wbig, biasp, tpg, gT);
  flash2<<<512, 256, 0, stream>>>(tpg, gT, Zp, Lpb);
  // out = sum(Zp)/(64*sum(L)) + f_b + x
  merge_out<<<2048, 256, 0, stream>>>(Zp, Lpb, fb, x, (float*)d_out);
}

// Round 8
// 212.219 us; speedup vs baseline: 1.1502x; 1.0303x over previous
//
#include <hip/hip_runtime.h>

// ---------- types ----------
typedef unsigned short u16;
typedef __bf16 bf16x8 __attribute__((ext_vector_type(8)));
typedef float f32x4 __attribute__((ext_vector_type(4)));
typedef float f32x16 __attribute__((ext_vector_type(16)));
typedef float float4v __attribute__((ext_vector_type(4)));
typedef unsigned short u16x8 __attribute__((ext_vector_type(8)));
typedef unsigned short u16x4 __attribute__((ext_vector_type(4)));

#define MFMA16(a, b, c) __builtin_amdgcn_mfma_f32_16x16x32_bf16(a, b, c, 0, 0, 0)
#define MFMA32(a, b, c) __builtin_amdgcn_mfma_f32_32x32x16_bf16(a, b, c, 0, 0, 0)

__device__ __forceinline__ u16 f2bf(float f) {
  union { float f; unsigned u; } v; v.f = f;
  unsigned r = v.u + 0x7fffu + ((v.u >> 16) & 1u);
  return (u16)(r >> 16);
}
__device__ __forceinline__ float bf2f(u16 b) {
  union { unsigned u; float f; } v; v.u = ((unsigned)b) << 16;
  return v.f;
}

// async global->LDS, 16B per lane; LDS dest must be wave-uniform base + lane*16
__device__ __forceinline__ void gload16(const void* g, void* l) {
  __builtin_amdgcn_global_load_lds(
      (__attribute__((address_space(1))) void*)g,
      (__attribute__((address_space(3))) void*)l, 16, 0, 0);
}

__device__ __forceinline__ unsigned cvtpk(float lo, float hi) {
  unsigned r;
  asm("v_cvt_pk_bf16_f32 %0, %1, %2" : "=v"(r) : "v"(lo), "v"(hi));
  return r;
}
// swap a.lanes[32:63] <-> b.lanes[0:31]
__device__ __forceinline__ void plswap(unsigned& a, unsigned& b) {
  asm volatile("v_permlane32_swap_b32 %0, %1" : "+v"(a), "+v"(b));
}

// ---------- kernel 1: prep_all ----------
// bid<256:  Wbig[bid] = row of theta_w·cw, biasp = theta_w·cb + theta_b
// bid<512:  Wbig[bid] = row of phi_w·cw,   biasp = phi_w·cb + phi_b
// bid>=512: o=bid-512: u = fw[o]·gw (in-block), Wbig[bid] = u·cw,
//           biasp = u·cb + fw[o]·gb         (V' = g·fw^T folded into weights)
__global__ __launch_bounds__(256) void prep_all(
    const float* __restrict__ cw, const float* __restrict__ tw,
    const float* __restrict__ pw, const float* __restrict__ gw,
    const float* __restrict__ fw,
    const float* __restrict__ cb, const float* __restrict__ tb,
    const float* __restrict__ pb, const float* __restrict__ gb,
    u16* __restrict__ Wbig, float* __restrict__ biasp) {
  const int t = threadIdx.x;
  const int bid = blockIdx.x;  // 0..767
  const int n3 = bid & 255;
  __shared__ float w3s[256];
  __shared__ float us[256];
  __shared__ float red[4];
  float pv;  // per-thread partial for the bias dot
  if (bid < 512) {
    const float* wsrc = bid < 256 ? tw : pw;
    w3s[t] = wsrc[(size_t)n3 * 256 + t];
    __syncthreads();
    float acc = 0.0f;
#pragma unroll 8
    for (int h = 0; h < 256; ++h) acc = fmaf(w3s[h], cw[(size_t)h * 256 + t], acc);
    Wbig[(size_t)bid * 256 + t] = f2bf(acc);
    pv = w3s[t] * cb[t];
  } else {
    w3s[t] = fw[(size_t)n3 * 256 + t];
    __syncthreads();
    float u = 0.0f;
#pragma unroll 8
    for (int h = 0; h < 256; ++h) u = fmaf(w3s[h], gw[(size_t)h * 256 + t], u);
    us[t] = u;
    __syncthreads();
    float acc = 0.0f;
#pragma unroll 8
    for (int k = 0; k < 256; ++k) acc = fmaf(us[k], cw[(size_t)k * 256 + t], acc);
    Wbig[(size_t)bid * 256 + t] = f2bf(acc);
    pv = us[t] * cb[t] + w3s[t] * gb[t];
  }
#pragma unroll
  for (int m = 1; m < 64; m <<= 1) pv += __shfl_xor(pv, m, 64);
  if ((t & 63) == 0) red[t >> 6] = pv;
  __syncthreads();
  if (t == 0) {
    float d = red[0] + red[1] + red[2] + red[3];
    biasp[bid] = d + (bid < 256 ? tb[n3] : bid < 512 ? pb[n3] : 0.0f);
  }
}

// ---------- kernel 2: tpg GEMM, fused f32->bf16 A conversion ----------
// y<4:  tpg[m][col] = x[m]·Wbig[col] + biasp[col]   (theta|phi, stride 512)
// y>=4: V' = x·Wv^T + bv, written TRANSPOSED to gT via LDS (coalesced)
__global__ __launch_bounds__(256) void gemm_tpg(
    const float* __restrict__ X, const u16* __restrict__ W,
    const float* __restrict__ bias, u16* __restrict__ tpg,
    u16* __restrict__ gT) {
  __shared__ u16 S[16384];
  u16* As = S;
  u16* Bs = S + 8192;
  const int t = threadIdx.x;
  const int lane = t & 63, w = t >> 6;
  const int brow = blockIdx.x * 128, bcol = blockIdx.y * 128;
  const int wr = (w >> 1) * 64, wc = (w & 1) * 64;
  f32x4 acc[4][4];
#pragma unroll
  for (int i = 0; i < 4; ++i)
#pragma unroll
    for (int j = 0; j < 4; ++j)
#pragma unroll
      for (int r = 0; r < 4; ++r) acc[i][j][r] = 0.0f;

  const int sr = t >> 3, sc8 = (t & 7) * 8;
  const u16* gW = W + (size_t)(bcol + sr) * 256 + sc8;
  const int ar = t & 127, ach = t >> 7;  // A staging: row, col-half
  const float* gX = X + (size_t)(brow + ar) * 256 + ach * 32;

  for (int kt = 0; kt < 256; kt += 64) {
#pragma unroll
    for (int c = 0; c < 4; ++c)
      gload16(gW + (size_t)c * 32 * 256 + kt, &Bs[c * 2048 + t * 8]);
    u16x8 pk[4];
#pragma unroll
    for (int j = 0; j < 4; ++j) {
      float4v v0 = *(const float4v*)(gX + kt + j * 8);
      float4v v1 = *(const float4v*)(gX + kt + j * 8 + 4);
#pragma unroll
      for (int e = 0; e < 4; ++e) { pk[j][e] = f2bf(v0[e]); pk[j][4 + e] = f2bf(v1[e]); }
    }
#pragma unroll
    for (int j = 0; j < 4; ++j) {
      int unit = (ach * 4 + j) ^ (ar & 7);
      *(u16x8*)(&As[ar * 64 + unit * 8]) = pk[j];
    }
    __syncthreads();
#pragma unroll
    for (int kk = 0; kk < 2; ++kk) {
      const int ko = kk * 32 + (lane >> 4) * 8;
      bf16x8 af[4], bfr[4];
#pragma unroll
      for (int i = 0; i < 4; ++i) {
        int R = wr + i * 16 + (lane & 15);
        int unit = (kk * 4 + (lane >> 4)) ^ (R & 7);
        af[i] = *(const bf16x8*)(&As[R * 64 + unit * 8]);
      }
#pragma unroll
      for (int j = 0; j < 4; ++j)
        bfr[j] = *(const bf16x8*)(&Bs[(wc + j * 16 + (lane & 15)) * 64 + ko]);
#pragma unroll
      for (int i = 0; i < 4; ++i)
#pragma unroll
        for (int j = 0; j < 4; ++j)
          acc[i][j] = MFMA16(af[i], bfr[j], acc[i][j]);
    }
    __syncthreads();
  }

  const int r0 = (lane >> 4) * 4, c0 = lane & 15;
  if (blockIdx.y < 4) {
    // theta|phi: direct row-major write, stride 512
#pragma unroll
    for (int i = 0; i < 4; ++i)
#pragma unroll
      for (int j = 0; j < 4; ++j) {
        const int col = bcol + wc + j * 16 + c0;
        const float bv = bias[col];
#pragma unroll
        for (int r = 0; r < 4; ++r) {
          const size_t o = (size_t)(brow + wr + i * 16 + r0 + r) * 512 + col;
          tpg[o] = f2bf(acc[i][j][r] + bv);
        }
      }
  } else {
    // V': LDS-transposed coalesced write.  S used as [128 cols][72] u16.
    const int vcb = bcol - 512;  // 0 or 128
    const int b = brow >> 12, n0 = brow & 4095;
#pragma unroll
    for (int h = 0; h < 2; ++h) {
      if (wr == h * 64) {
#pragma unroll
        for (int i = 0; i < 4; ++i)
#pragma unroll
          for (int j = 0; j < 4; ++j) {
            const int col = wc + j * 16 + c0;                 // 0..127
            const float bv = bias[bcol + col];
            const int rowl = i * 16 + r0;                     // 0..60, mult of 4
            u16x4 ov;
#pragma unroll
            for (int r = 0; r < 4; ++r) ov[r] = f2bf(acc[i][j][r] + bv);
            *(u16x4*)(&S[col * 72 + rowl]) = ov;
          }
      }
      __syncthreads();
#pragma unroll
      for (int k = 0; k < 4; ++k) {
        const int col = k * 32 + (t >> 3);                    // 0..127
        const int mch = (t & 7) * 8;                          // 0..56
        u16x8 v = *(const u16x8*)(&S[col * 72 + mch]);
        *(u16x8*)(&gT[((size_t)((b << 8) + vcb + col)) * 4096 + n0 + h * 64 + mch]) = v;
      }
      __syncthreads();
    }
  }
}

// ---------- kernel 3: flash attention (round-5/7 structure, unchanged) ----------
__global__ __launch_bounds__(256, 2) void flash2(
    const u16* __restrict__ tpg, const u16* __restrict__ gT,
    u16* __restrict__ Zp, u16* __restrict__ Lpb) {
  __shared__ u16 Kl[2][32 * 256];  // rows=kv(32), swz c16^row
  __shared__ u16 Vl[2][256 * 32];  // rows=d(256), swz c16^((row>>1)&3)

  const int t = threadIdx.x;
  const int lane = t & 63, w = t >> 6;
  const int l31 = lane & 31, hi = lane >> 5;
  const int bid = blockIdx.x;
  const int b = bid >> 7;
  const int quarter = (bid >> 5) & 3;
  const int qt = bid & 31;
  const int q0 = qt * 128 + w * 32;
  const int kv0 = quarter * 1024;

  bf16x8 q[16];
  {
    const u16* qp = tpg + (size_t)(b * 4096 + q0 + l31) * 512 + hi * 8;
#pragma unroll
    for (int ks = 0; ks < 16; ++ks) q[ks] = *(const bf16x8*)(qp + ks * 16);
  }

  f32x16 zacc[8];
#pragma unroll
  for (int i = 0; i < 8; ++i)
#pragma unroll
    for (int j = 0; j < 16; ++j) zacc[i][j] = 0.0f;
  float ell = 0.0f;

  const int ksr = t >> 5, ksc = t & 31;

  auto stage = [&](int tile, int bi) {
    const size_t krow0 = (size_t)(b * 4096 + kv0 + tile * 32);
#pragma unroll
    for (int ch = 0; ch < 4; ++ch) {
      int r = ch * 8 + ksr;
      gload16(tpg + (krow0 + r) * 512 + 256 + ((ksc ^ r) * 8), &Kl[bi][ch * 2048 + t * 8]);
    }
#pragma unroll
    for (int ch = 0; ch < 4; ++ch) {
      int u = ch * 256 + t;
      int r = u >> 2, c16 = u & 3;
      gload16(gT + (size_t)(b * 256 + r) * 4096 + kv0 + tile * 32 + ((c16 ^ ((r >> 1) & 3)) * 8),
              &Vl[bi][u * 8]);
    }
  };

  stage(0, 0);
  __syncthreads();

  for (int tile = 0; tile < 32; ++tile) {
    const int cur = tile & 1;
    if (tile + 1 < 32) stage(tile + 1, cur ^ 1);

    // S^T = K * Q^T
    f32x16 s;
#pragma unroll
    for (int j = 0; j < 16; ++j) s[j] = 0.0f;
    const u16* kb = &Kl[cur][0];
    __builtin_amdgcn_s_setprio(1);
#pragma unroll
    for (int ks = 0; ks < 16; ++ks) {
      bf16x8 kf = *(const bf16x8*)(kb + l31 * 256 + (((2 * ks + hi) ^ l31) * 8));
      s = MFMA32(kf, q[ks], s);
    }
    __builtin_amdgcn_s_setprio(0);

    // in-register softmax numerators -> PV A-frags
    bf16x8 pa[2];
#pragma unroll
    for (int half = 0; half < 2; ++half) {
      float p[8];
#pragma unroll
      for (int g = 0; g < 8; ++g) {
        p[g] = __builtin_amdgcn_exp2f(s[half * 8 + g] * 0.09016844f);
        ell += p[g];
      }
      unsigned x0 = cvtpk(p[0], p[1]), y0 = cvtpk(p[4], p[5]);
      unsigned x1 = cvtpk(p[2], p[3]), y1 = cvtpk(p[6], p[7]);
      plswap(x0, y0);
      plswap(x1, y1);
      union { unsigned u[4]; bf16x8 v; } cc;
      cc.u[0] = x0; cc.u[1] = x1; cc.u[2] = y0; cc.u[3] = y1;
      pa[half] = cc.v;
    }

    // Z += P * V'
    const u16* vb = &Vl[cur][0];
    __builtin_amdgcn_s_setprio(1);
#pragma unroll
    for (int ks2 = 0; ks2 < 2; ++ks2) {
#pragma unroll
      for (int nt = 0; nt < 8; ++nt) {
        int row = nt * 32 + l31;
        bf16x8 vv = *(const bf16x8*)(vb + row * 32 + (((2 * ks2 + hi) ^ ((row >> 1) & 3)) * 8));
        zacc[nt] = MFMA32(pa[ks2], vv, zacc[nt]);
      }
    }
    __builtin_amdgcn_s_setprio(0);
    __syncthreads();
  }

  ell += __shfl_xor(ell, 32, 64);

#pragma unroll
  for (int g = 0; g < 16; ++g) {
    int r = (g & 3) + 8 * (g >> 2) + 4 * hi;
    size_t rowoff = ((size_t)(quarter * 16384 + b * 4096 + q0 + r)) * 256 + l31;
#pragma unroll
    for (int nt = 0; nt < 8; ++nt) Zp[rowoff + nt * 32] = f2bf(zacc[nt][g]);
  }
  if (lane < 32) Lpb[quarter * 16384 + b * 4096 + q0 + l31] = f2bf(ell);
}

// ---------- kernel 4: elementwise merge: out = sum(Zp)/(64*sum(L)) + fb + x ----------
__global__ __launch_bounds__(256) void merge_out(
    const u16* __restrict__ Zp, const u16* __restrict__ Lpb,
    const float* __restrict__ fb, const float* __restrict__ x,
    float* __restrict__ out) {
  const int idx = blockIdx.x * 256 + threadIdx.x;  // 524288 threads, 8 cols each
  const int m = idx >> 5;
  const int c = (idx & 31) * 8;
  const float l = bf2f(Lpb[m]) + bf2f(Lpb[16384 + m]) + bf2f(Lpb[32768 + m]) +
                  bf2f(Lpb[49152 + m]);
  const float inv = 1.0f / (l * 64.0f);
  float acc[8];
#pragma unroll
  for (int j = 0; j < 8; ++j) acc[j] = 0.0f;
#pragma unroll
  for (int qd = 0; qd < 4; ++qd) {
    u16x8 v = *(const u16x8*)(Zp + ((size_t)(qd * 16384) + m) * 256 + c);
#pragma unroll
    for (int j = 0; j < 8; ++j) acc[j] += bf2f(v[j]);
  }
  const float4v fb0 = *(const float4v*)(fb + c);
  const float4v fb1 = *(const float4v*)(fb + c + 4);
  const float4v x0 = *(const float4v*)(x + (size_t)m * 256 + c);
  const float4v x1 = *(const float4v*)(x + (size_t)m * 256 + c + 4);
  float4v o0, o1;
#pragma unroll
  for (int j = 0; j < 4; ++j) {
    o0[j] = acc[j] * inv + fb0[j] + x0[j];
    o1[j] = acc[4 + j] * inv + fb1[j] + x1[j];
  }
  *(float4v*)(out + (size_t)m * 256 + c) = o0;
  *(float4v*)(out + (size_t)m * 256 + c + 4) = o1;
}

// ---------- launch ----------
extern "C" void kernel_launch(void* const* d_in, const int* in_sizes, int n_in,
                              void* d_out, int out_size, void* d_ws, size_t ws_size,
                              hipStream_t stream) {
  const float* x  = (const float*)d_in[0];
  const float* cw = (const float*)d_in[1];
  const float* cb = (const float*)d_in[2];
  const float* tw = (const float*)d_in[3];
  const float* tb = (const float*)d_in[4];
  const float* pw = (const float*)d_in[5];
  const float* pb = (const float*)d_in[6];
  const float* gw = (const float*)d_in[7];
  const float* gb = (const float*)d_in[8];
  const float* fw = (const float*)d_in[9];
  const float* fb = (const float*)d_in[10];

  char* ws = (char*)d_ws;
  // layout (peak ~59.2 MB)
  u16*   tpg   = (u16*)(ws);                  // [16384][512] theta|phi     16777216 B
  u16*   gT    = (u16*)(ws + 16777216);       // [4][256][4096] V'           8388608 B
  u16*   Zp    = (u16*)(ws + 25165824);       // [4][16384][256] bf16       33554432 B
  u16*   Lpb   = (u16*)(ws + 58720256);       // [4][16384] bf16              131072 B
  u16*   Wbig  = (u16*)(ws + 58851328);       // [768][256] bf16              393216 B
  float* biasp = (float*)(ws + 59244544);     // [768] f32                      3072 B

  // all weight folding in one kernel (theta, phi, Wv=(fw·gw)·cw + biases)
  prep_all<<<768, 256, 0, stream>>>(cw, tw, pw, gw, fw, cb, tb, pb, gb, Wbig, biasp);
  // theta|phi -> tpg (stride 512); V' -> gT (LDS-transposed coalesced write)
  gemm_tpg<<<dim3(128, 6), 256, 0, stream>>>(x, Wbig, biasp, tpg, gT);
  flash2<<<512, 256, 0, stream>>>(tpg, gT, Zp, Lpb);
  // out = sum(Zp)/(64*sum(L)) + f_b + x
  merge_out<<<2048, 256, 0, stream>>>(Zp, Lpb, fb, x, (float*)d_out);
}

// Round 9
// 207.186 us; speedup vs baseline: 1.1782x; 1.0243x over previous
//
#include <hip/hip_runtime.h>

// ---------- types ----------
typedef unsigned short u16;
typedef __bf16 bf16x8 __attribute__((ext_vector_type(8)));
typedef float f32x4 __attribute__((ext_vector_type(4)));
typedef float f32x16 __attribute__((ext_vector_type(16)));
typedef float float4v __attribute__((ext_vector_type(4)));
typedef unsigned short u16x8 __attribute__((ext_vector_type(8)));
typedef unsigned short u16x4 __attribute__((ext_vector_type(4)));

#define MFMA16(a, b, c) __builtin_amdgcn_mfma_f32_16x16x32_bf16(a, b, c, 0, 0, 0)
#define MFMA32(a, b, c) __builtin_amdgcn_mfma_f32_32x32x16_bf16(a, b, c, 0, 0, 0)

__device__ __forceinline__ u16 f2bf(float f) {
  union { float f; unsigned u; } v; v.f = f;
  unsigned r = v.u + 0x7fffu + ((v.u >> 16) & 1u);
  return (u16)(r >> 16);
}
__device__ __forceinline__ float bf2f(u16 b) {
  union { unsigned u; float f; } v; v.u = ((unsigned)b) << 16;
  return v.f;
}

// async global->LDS, 16B per lane; LDS dest must be wave-uniform base + lane*16
__device__ __forceinline__ void gload16(const void* g, void* l) {
  __builtin_amdgcn_global_load_lds(
      (__attribute__((address_space(1))) void*)g,
      (__attribute__((address_space(3))) void*)l, 16, 0, 0);
}

__device__ __forceinline__ unsigned cvtpk(float lo, float hi) {
  unsigned r;
  asm("v_cvt_pk_bf16_f32 %0, %1, %2" : "=v"(r) : "v"(lo), "v"(hi));
  return r;
}
// swap a.lanes[32:63] <-> b.lanes[0:31]
__device__ __forceinline__ void plswap(unsigned& a, unsigned& b) {
  asm volatile("v_permlane32_swap_b32 %0, %1" : "+v"(a), "+v"(b));
}

// ---------- kernel 1: prep_all ----------
// bid<256:  Wbig[bid] = theta_w·cw row, biasp = theta_w·cb + theta_b
// bid<512:  Wbig[bid] = phi_w·cw row,   biasp = phi_w·cb + phi_b
// bid<768:  o=bid-512: u = fw[o]·gw, Wbig[bid] = u·cw, biasp = u·cb + fw[o]·gb
// bid>=768: x -> xb bf16 conversion
__global__ __launch_bounds__(256) void prep_all(
    const float* __restrict__ cw, const float* __restrict__ tw,
    const float* __restrict__ pw, const float* __restrict__ gw,
    const float* __restrict__ fw,
    const float* __restrict__ cb, const float* __restrict__ tb,
    const float* __restrict__ pb, const float* __restrict__ gb,
    const float* __restrict__ X,
    u16* __restrict__ Wbig, float* __restrict__ biasp, u16* __restrict__ xb) {
  const int t = threadIdx.x;
  const int bid = blockIdx.x;
  if (bid >= 768) {
    const int idx = (bid - 768) * 256 + t;  // 1048576 float4 units
    float4v v = *(const float4v*)(X + (size_t)idx * 4);
    u16x4 o;
#pragma unroll
    for (int i = 0; i < 4; ++i) o[i] = f2bf(v[i]);
    *(u16x4*)(xb + (size_t)idx * 4) = o;
    return;
  }
  const int n3 = bid & 255;
  __shared__ float w3s[256];
  __shared__ float us[256];
  __shared__ float red[4];
  float pv;
  if (bid < 512) {
    const float* wsrc = bid < 256 ? tw : pw;
    w3s[t] = wsrc[(size_t)n3 * 256 + t];
    __syncthreads();
    float acc = 0.0f;
#pragma unroll 8
    for (int h = 0; h < 256; ++h) acc = fmaf(w3s[h], cw[(size_t)h * 256 + t], acc);
    Wbig[(size_t)bid * 256 + t] = f2bf(acc);
    pv = w3s[t] * cb[t];
  } else {
    w3s[t] = fw[(size_t)n3 * 256 + t];
    __syncthreads();
    float u = 0.0f;
#pragma unroll 8
    for (int h = 0; h < 256; ++h) u = fmaf(w3s[h], gw[(size_t)h * 256 + t], u);
    us[t] = u;
    __syncthreads();
    float acc = 0.0f;
#pragma unroll 8
    for (int k = 0; k < 256; ++k) acc = fmaf(us[k], cw[(size_t)k * 256 + t], acc);
    Wbig[(size_t)bid * 256 + t] = f2bf(acc);
    pv = us[t] * cb[t] + w3s[t] * gb[t];
  }
#pragma unroll
  for (int m = 1; m < 64; m <<= 1) pv += __shfl_xor(pv, m, 64);
  if ((t & 63) == 0) red[t >> 6] = pv;
  __syncthreads();
  if (t == 0) {
    float d = red[0] + red[1] + red[2] + red[3];
    biasp[bid] = d + (bid < 256 ? tb[n3] : bid < 512 ? pb[n3] : 0.0f);
  }
}

// ---------- kernel 2: tpg GEMM (bf16 A via global_load_lds, m97 path) ----------
// y<4:  tpg[m][col] = xb[m]·Wbig[col] + biasp[col]   (theta|phi, stride 512)
// y>=4: V' = x·Wv^T + bv, written TRANSPOSED to gT via LDS (coalesced)
__global__ __launch_bounds__(256) void gemm_tpg(
    const u16* __restrict__ A, const u16* __restrict__ W,
    const float* __restrict__ bias, u16* __restrict__ tpg,
    u16* __restrict__ gT) {
  __shared__ u16 S[16384];
  u16* As = S;
  u16* Bs = S + 8192;
  const int t = threadIdx.x;
  const int lane = t & 63, w = t >> 6;
  const int brow = blockIdx.x * 128, bcol = blockIdx.y * 128;
  const int wr = (w >> 1) * 64, wc = (w & 1) * 64;
  f32x4 acc[4][4];
#pragma unroll
  for (int i = 0; i < 4; ++i)
#pragma unroll
    for (int j = 0; j < 4; ++j)
#pragma unroll
      for (int r = 0; r < 4; ++r) acc[i][j][r] = 0.0f;

  const int sr = t >> 3, sc8 = (t & 7) * 8;
  const u16* gA = A + (size_t)(brow + sr) * 256 + sc8;
  const u16* gW = W + (size_t)(bcol + sr) * 256 + sc8;

  for (int kt = 0; kt < 256; kt += 64) {
#pragma unroll
    for (int c = 0; c < 4; ++c) {
      gload16(gA + (size_t)c * 32 * 256 + kt, &As[c * 2048 + t * 8]);
      gload16(gW + (size_t)c * 32 * 256 + kt, &Bs[c * 2048 + t * 8]);
    }
    __syncthreads();
#pragma unroll
    for (int kk = 0; kk < 2; ++kk) {
      const int ko = kk * 32 + (lane >> 4) * 8;
      bf16x8 af[4], bfr[4];
#pragma unroll
      for (int i = 0; i < 4; ++i)
        af[i] = *(const bf16x8*)(&As[(wr + i * 16 + (lane & 15)) * 64 + ko]);
#pragma unroll
      for (int j = 0; j < 4; ++j)
        bfr[j] = *(const bf16x8*)(&Bs[(wc + j * 16 + (lane & 15)) * 64 + ko]);
#pragma unroll
      for (int i = 0; i < 4; ++i)
#pragma unroll
        for (int j = 0; j < 4; ++j)
          acc[i][j] = MFMA16(af[i], bfr[j], acc[i][j]);
    }
    __syncthreads();
  }

  const int r0 = (lane >> 4) * 4, c0 = lane & 15;
  if (blockIdx.y < 4) {
    // theta|phi: direct row-major write, stride 512
#pragma unroll
    for (int i = 0; i < 4; ++i)
#pragma unroll
      for (int j = 0; j < 4; ++j) {
        const int col = bcol + wc + j * 16 + c0;
        const float bv = bias[col];
#pragma unroll
        for (int r = 0; r < 4; ++r) {
          const size_t o = (size_t)(brow + wr + i * 16 + r0 + r) * 512 + col;
          tpg[o] = f2bf(acc[i][j][r] + bv);
        }
      }
  } else {
    // V': LDS-transposed coalesced write.  S used as [128 cols][72] u16.
    const int vcb = bcol - 512;  // 0 or 128
    const int b = brow >> 12, n0 = brow & 4095;
#pragma unroll
    for (int h = 0; h < 2; ++h) {
      if (wr == h * 64) {
#pragma unroll
        for (int i = 0; i < 4; ++i)
#pragma unroll
          for (int j = 0; j < 4; ++j) {
            const int col = wc + j * 16 + c0;                 // 0..127
            const float bv = bias[bcol + col];
            const int rowl = i * 16 + r0;                     // 0..60, mult of 4
            u16x4 ov;
#pragma unroll
            for (int r = 0; r < 4; ++r) ov[r] = f2bf(acc[i][j][r] + bv);
            *(u16x4*)(&S[col * 72 + rowl]) = ov;
          }
      }
      __syncthreads();
#pragma unroll
      for (int k = 0; k < 4; ++k) {
        const int col = k * 32 + (t >> 3);                    // 0..127
        const int mch = (t & 7) * 8;                          // 0..56
        u16x8 v = *(const u16x8*)(&S[col * 72 + mch]);
        *(u16x8*)(&gT[((size_t)((b << 8) + vcb + col)) * 4096 + n0 + h * 64 + mch]) = v;
      }
      __syncthreads();
    }
  }
}

// ---------- kernel 3: flash attention (counted vmcnt + XCD swizzle) ----------
__global__ __launch_bounds__(256, 2) void flash2(
    const u16* __restrict__ tpg, const u16* __restrict__ gT,
    u16* __restrict__ Zp, u16* __restrict__ Lpb) {
  __shared__ u16 Kl[2][32 * 256];  // rows=kv(32), swz c16^row
  __shared__ u16 Vl[2][256 * 32];  // rows=d(256), swz c16^((row>>1)&3)

  const int t = threadIdx.x;
  const int lane = t & 63, w = t >> 6;
  const int l31 = lane & 31, hi = lane >> 5;
  // XCD-aware swizzle (512 = 8 XCDs x 64): blocks sharing a KV quarter
  // cluster on one XCD for L2 reuse of K/V tiles.
  const int bid = ((blockIdx.x & 7) << 6) | (blockIdx.x >> 3);
  const int b = bid >> 7;
  const int quarter = (bid >> 5) & 3;
  const int qt = bid & 31;
  const int q0 = qt * 128 + w * 32;
  const int kv0 = quarter * 1024;

  bf16x8 q[16];
  {
    const u16* qp = tpg + (size_t)(b * 4096 + q0 + l31) * 512 + hi * 8;
#pragma unroll
    for (int ks = 0; ks < 16; ++ks) q[ks] = *(const bf16x8*)(qp + ks * 16);
  }

  f32x16 zacc[8];
#pragma unroll
  for (int i = 0; i < 8; ++i)
#pragma unroll
    for (int j = 0; j < 16; ++j) zacc[i][j] = 0.0f;
  float ell = 0.0f;

  const int ksr = t >> 5, ksc = t & 31;

  auto stage = [&](int tile, int bi) {
    const size_t krow0 = (size_t)(b * 4096 + kv0 + tile * 32);
#pragma unroll
    for (int ch = 0; ch < 4; ++ch) {
      int r = ch * 8 + ksr;
      gload16(tpg + (krow0 + r) * 512 + 256 + ((ksc ^ r) * 8), &Kl[bi][ch * 2048 + t * 8]);
    }
#pragma unroll
    for (int ch = 0; ch < 4; ++ch) {
      int u = ch * 256 + t;
      int r = u >> 2, c16 = u & 3;
      gload16(gT + (size_t)(b * 256 + r) * 4096 + kv0 + tile * 32 + ((c16 ^ ((r >> 1) & 3)) * 8),
              &Vl[bi][u * 8]);
    }
  };

  stage(0, 0);
  __syncthreads();

  for (int tile = 0; tile < 32; ++tile) {
    const int cur = tile & 1;
    // T4-lite: issue next-tile prefetch, wait only for CURRENT tile's loads
    // (own wave: vmcnt(8) leaves the 8 just-issued loads in flight), then
    // raw barrier publishes all waves' stage(t) writes. No full drain.
    if (tile + 1 < 32) {
      stage(tile + 1, cur ^ 1);
      asm volatile("s_waitcnt vmcnt(8)" ::: "memory");
    } else {
      asm volatile("s_waitcnt vmcnt(0)" ::: "memory");
    }
    asm volatile("s_barrier" ::: "memory");

    // S^T = K * Q^T
    f32x16 s;
#pragma unroll
    for (int j = 0; j < 16; ++j) s[j] = 0.0f;
    const u16* kb = &Kl[cur][0];
    __builtin_amdgcn_s_setprio(1);
#pragma unroll
    for (int ks = 0; ks < 16; ++ks) {
      bf16x8 kf = *(const bf16x8*)(kb + l31 * 256 + (((2 * ks + hi) ^ l31) * 8));
      s = MFMA32(kf, q[ks], s);
    }
    __builtin_amdgcn_s_setprio(0);

    // in-register softmax numerators -> PV A-frags
    bf16x8 pa[2];
#pragma unroll
    for (int half = 0; half < 2; ++half) {
      float p[8];
#pragma unroll
      for (int g = 0; g < 8; ++g) {
        p[g] = __builtin_amdgcn_exp2f(s[half * 8 + g] * 0.09016844f);
        ell += p[g];
      }
      unsigned x0 = cvtpk(p[0], p[1]), y0 = cvtpk(p[4], p[5]);
      unsigned x1 = cvtpk(p[2], p[3]), y1 = cvtpk(p[6], p[7]);
      plswap(x0, y0);
      plswap(x1, y1);
      union { unsigned u[4]; bf16x8 v; } cc;
      cc.u[0] = x0; cc.u[1] = x1; cc.u[2] = y0; cc.u[3] = y1;
      pa[half] = cc.v;
    }

    // Z += P * V'
    const u16* vb = &Vl[cur][0];
    __builtin_amdgcn_s_setprio(1);
#pragma unroll
    for (int ks2 = 0; ks2 < 2; ++ks2) {
#pragma unroll
      for (int nt = 0; nt < 8; ++nt) {
        int row = nt * 32 + l31;
        bf16x8 vv = *(const bf16x8*)(vb + row * 32 + (((2 * ks2 + hi) ^ ((row >> 1) & 3)) * 8));
        zacc[nt] = MFMA32(pa[ks2], vv, zacc[nt]);
      }
    }
    __builtin_amdgcn_s_setprio(0);
    // read-protection barrier: all waves done reading buf cur before any
    // wave's next-iteration stage overwrites it
    asm volatile("s_barrier" ::: "memory");
  }

  ell += __shfl_xor(ell, 32, 64);

#pragma unroll
  for (int g = 0; g < 16; ++g) {
    int r = (g & 3) + 8 * (g >> 2) + 4 * hi;
    size_t rowoff = ((size_t)(quarter * 16384 + b * 4096 + q0 + r)) * 256 + l31;
#pragma unroll
    for (int nt = 0; nt < 8; ++nt) Zp[rowoff + nt * 32] = f2bf(zacc[nt][g]);
  }
  if (lane < 32) Lpb[quarter * 16384 + b * 4096 + q0 + l31] = f2bf(ell);
}

// ---------- kernel 4: elementwise merge: out = sum(Zp)/(64*sum(L)) + fb + x ----------
__global__ __launch_bounds__(256) void merge_out(
    const u16* __restrict__ Zp, const u16* __restrict__ Lpb,
    const float* __restrict__ fb, const float* __restrict__ x,
    float* __restrict__ out) {
  const int idx = blockIdx.x * 256 + threadIdx.x;  // 524288 threads, 8 cols each
  const int m = idx >> 5;
  const int c = (idx & 31) * 8;
  const float l = bf2f(Lpb[m]) + bf2f(Lpb[16384 + m]) + bf2f(Lpb[32768 + m]) +
                  bf2f(Lpb[49152 + m]);
  const float inv = 1.0f / (l * 64.0f);
  float acc[8];
#pragma unroll
  for (int j = 0; j < 8; ++j) acc[j] = 0.0f;
#pragma unroll
  for (int qd = 0; qd < 4; ++qd) {
    u16x8 v = *(const u16x8*)(Zp + ((size_t)(qd * 16384) + m) * 256 + c);
#pragma unroll
    for (int j = 0; j < 8; ++j) acc[j] += bf2f(v[j]);
  }
  const float4v fb0 = *(const float4v*)(fb + c);
  const float4v fb1 = *(const float4v*)(fb + c + 4);
  const float4v x0 = *(const float4v*)(x + (size_t)m * 256 + c);
  const float4v x1 = *(const float4v*)(x + (size_t)m * 256 + c + 4);
  float4v o0, o1;
#pragma unroll
  for (int j = 0; j < 4; ++j) {
    o0[j] = acc[j] * inv + fb0[j] + x0[j];
    o1[j] = acc[4 + j] * inv + fb1[j] + x1[j];
  }
  *(float4v*)(out + (size_t)m * 256 + c) = o0;
  *(float4v*)(out + (size_t)m * 256 + c + 4) = o1;
}

// ---------- launch ----------
extern "C" void kernel_launch(void* const* d_in, const int* in_sizes, int n_in,
                              void* d_out, int out_size, void* d_ws, size_t ws_size,
                              hipStream_t stream) {
  const float* x  = (const float*)d_in[0];
  const float* cw = (const float*)d_in[1];
  const float* cb = (const float*)d_in[2];
  const float* tw = (const float*)d_in[3];
  const float* tb = (const float*)d_in[4];
  const float* pw = (const float*)d_in[5];
  const float* pb = (const float*)d_in[6];
  const float* gw = (const float*)d_in[7];
  const float* gb = (const float*)d_in[8];
  const float* fw = (const float*)d_in[9];
  const float* fb = (const float*)d_in[10];

  char* ws = (char*)d_ws;
  // layout (peak ~67.6 MB; round-1 proved >= 67.9 MB available)
  u16*   tpg   = (u16*)(ws);                  // [16384][512] theta|phi     16777216 B
  u16*   gT    = (u16*)(ws + 16777216);       // [4][256][4096] V'           8388608 B
  u16*   Zp    = (u16*)(ws + 25165824);       // [4][16384][256] bf16       33554432 B
  u16*   Lpb   = (u16*)(ws + 58720256);       // [4][16384] bf16              131072 B
  u16*   Wbig  = (u16*)(ws + 58851328);       // [768][256] bf16              393216 B
  float* biasp = (float*)(ws + 59244544);     // [768] f32                      3072 B
  u16*   xb    = (u16*)(ws + 59247616);       // [16384][256] bf16           8388608 B

  // weight folding + x->bf16
  prep_all<<<4864, 256, 0, stream>>>(cw, tw, pw, gw, fw, cb, tb, pb, gb, x,
                                     Wbig, biasp, xb);
  // theta|phi -> tpg (stride 512); V' -> gT (LDS-transposed coalesced write)
  gemm_tpg<<<dim3(128, 6), 256, 0, stream>>>(xb, Wbig, biasp, tpg, gT);
  flash2<<<512, 256, 0, stream>>>(tpg, gT, Zp, Lpb);
  // out = sum(Zp)/(64*sum(L)) + f_b + x
  merge_out<<<2048, 256, 0, stream>>>(Zp, Lpb, fb, x, (float*)d_out);
}